// Round 3
// baseline (298.185 us; speedup 1.0000x reference)
//
#include <hip/hip_runtime.h>
#include <math.h>

// Problem constants (fixed by the reference): N=8, B=4096, D=1024.
#define NN 8
#define BB 4096
#define DD 1024
#define LOG_2PI 1.8378770664093453f

// One block per row b (256 threads x 4 elems = D=1024).
// R3: make the 16-load staging STICK.
//  - __launch_bounds__(256,4): 4 waves/EU target -> 128-VGPR budget, so the
//    compiler may hold 64 VGPRs of staged float4s (R2's default heuristic
//    sank them back into the loop; VGPR_Count was 48 -> MLP of only 2).
//  - sched_barrier(0) after the load loop: machine scheduler may not move
//    the loads below it. Scan consumes M/L in issue order -> incremental
//    vmcnt(N) waits, single latency exposure.
__global__ __launch_bounds__(256, 4) void mpc_kernel(
    const float* __restrict__ means,
    const float* __restrict__ logsig,
    float* __restrict__ out_mean,
    float* __restrict__ out_logvar,
    float* __restrict__ out_logz)
{
    const int b = blockIdx.x;
    const int t = threadIdx.x;
    const size_t rowoff = (size_t)b * DD + (size_t)t * 4;
    const size_t plane = (size_t)BB * DD;

    // ---- stage: issue all 16 global_load_dwordx4 back-to-back ----
    float4 M[NN], L[NN];
#pragma unroll
    for (int n = 0; n < NN; ++n) {
        M[n] = *(const float4*)(means + (size_t)n * plane + rowoff);
        L[n] = *(const float4*)(logsig + (size_t)n * plane + rowoff);
    }
    __builtin_amdgcn_sched_barrier(0);  // loads may not sink past this point

    // ---- scan ----
    float m1[4], v1[4], iv1[4];
    {
        float m[4] = {M[0].x, M[0].y, M[0].z, M[0].w};
        float l[4] = {L[0].x, L[0].y, L[0].z, L[0].w};
#pragma unroll
        for (int j = 0; j < 4; ++j) {
            m1[j]  = m[j];
            v1[j]  = __expf(l[j]);
            iv1[j] = __expf(-l[j]);
        }
    }

    float z = 0.0f;

#pragma unroll
    for (int n = 1; n < NN; ++n) {
        float m2[4] = {M[n].x, M[n].y, M[n].z, M[n].w};
        float l2[4] = {L[n].x, L[n].y, L[n].z, L[n].w};
#pragma unroll
        for (int j = 0; j < 4; ++j) {
            float v2  = __expf(l2[j]);
            float iv2 = __expf(-l2[j]);
            float s   = v1[j] + v2 + 1e-6f;
            float diff = m1[j] - m2[j];
            z += diff * diff * __builtin_amdgcn_rcpf(s) + __logf(s);
            float iv_new = iv1[j] + iv2;
            float cvar   = __builtin_amdgcn_rcpf(iv_new);
            m1[j]  = cvar * (m1[j] * iv1[j] + m2[j] * iv2);
            v1[j]  = cvar;
            iv1[j] = iv_new;
        }
    }

    // ---- elementwise outputs ----
    float4 om = make_float4(m1[0], m1[1], m1[2], m1[3]);
    float4 ol = make_float4(__logf(v1[0]), __logf(v1[1]),
                            __logf(v1[2]), __logf(v1[3]));
    *(float4*)(out_mean + rowoff)   = om;
    *(float4*)(out_logvar + rowoff) = ol;

    // ---- row reduction of z (256 threads = 4 waves of 64) ----
#pragma unroll
    for (int o = 32; o > 0; o >>= 1)
        z += __shfl_down(z, o, 64);

    __shared__ float sz[4];
    const int wave = t >> 6;
    const int lane = t & 63;
    if (lane == 0) sz[wave] = z;
    __syncthreads();
    if (t == 0) {
        float total = sz[0] + sz[1] + sz[2] + sz[3];
        out_logz[b] = -0.5f * (total + (float)((NN - 1) * DD) * LOG_2PI);
    }
}

extern "C" void kernel_launch(void* const* d_in, const int* in_sizes, int n_in,
                              void* d_out, int out_size, void* d_ws, size_t ws_size,
                              hipStream_t stream) {
    const float* means  = (const float*)d_in[0];
    const float* logsig = (const float*)d_in[1];
    float* out = (float*)d_out;
    float* out_mean   = out;
    float* out_logvar = out + (size_t)BB * DD;
    float* out_logz   = out + 2 * (size_t)BB * DD;
    mpc_kernel<<<BB, 256, 0, stream>>>(means, logsig, out_mean, out_logvar, out_logz);
}

// Round 5
// 283.573 us; speedup vs baseline: 1.0515x; 1.0515x over previous
//
#include <hip/hip_runtime.h>
#include <math.h>

// Problem constants (fixed by the reference): N=8, B=4096, D=1024.
#define NN 8
#define BB 4096
#define DD 1024
#define LOG_2PI 1.8378770664093453f

// R5: structural MLP via LDS staging (compiler cannot sink it).
// Each of 256 threads issues 16 global_load_lds (width 16B) DMAs covering
// all 8 means-planes + 8 logsig-planes of row b (64 KB LDS), then one
// barrier drain. Scan reads LDS (ds_read_b128, conflict-free). 2 blocks/CU
// -> 128 KB DMA in flight per CU -> BW-saturating; next block's DMA
// overlaps this block's compute.

#define GLOAD_LDS16(g, l)                                                  \
    __builtin_amdgcn_global_load_lds(                                      \
        (const __attribute__((address_space(1))) unsigned int*)(g),        \
        (__attribute__((address_space(3))) unsigned int*)(l), 16, 0, 0)

__global__ __launch_bounds__(256) void mpc_kernel(
    const float* __restrict__ means,
    const float* __restrict__ logsig,
    float* __restrict__ out_mean,
    float* __restrict__ out_logvar,
    float* __restrict__ out_logz)
{
    __shared__ float smem[16 * DD];   // [0..8): means planes, [8..16): logsig

    const int b = blockIdx.x;
    const int t = threadIdx.x;
    const int wave = t >> 6;
    const size_t rowoff = (size_t)b * DD + (size_t)t * 4;
    const size_t plane = (size_t)BB * DD;

    // ---- stage: 16 DMA loads, wave-uniform LDS base + lane*16 ----
#pragma unroll
    for (int n = 0; n < NN; ++n) {
        const float* gm = means  + (size_t)n * plane + rowoff;
        const float* gl = logsig + (size_t)n * plane + rowoff;
        float* lm = &smem[n * DD + wave * 256];          // wave-uniform
        float* ll = &smem[(NN + n) * DD + wave * 256];   // wave-uniform
        GLOAD_LDS16(gm, lm);
        GLOAD_LDS16(gl, ll);
    }
    __syncthreads();   // single vmcnt(0) drain for all 16 DMAs

    // ---- scan (4 elements/thread, read from LDS) ----
    float m1[4], v1[4], iv1[4];
    {
        float4 mm = *(const float4*)&smem[0 * DD + t * 4];
        float4 ll = *(const float4*)&smem[NN * DD + t * 4];
        float m[4] = {mm.x, mm.y, mm.z, mm.w};
        float l[4] = {ll.x, ll.y, ll.z, ll.w};
#pragma unroll
        for (int j = 0; j < 4; ++j) {
            m1[j]  = m[j];
            v1[j]  = __expf(l[j]);
            iv1[j] = __expf(-l[j]);
        }
    }

    float z = 0.0f;

#pragma unroll
    for (int n = 1; n < NN; ++n) {
        float4 mm = *(const float4*)&smem[n * DD + t * 4];
        float4 ll = *(const float4*)&smem[(NN + n) * DD + t * 4];
        float m2[4] = {mm.x, mm.y, mm.z, mm.w};
        float l2[4] = {ll.x, ll.y, ll.z, ll.w};
#pragma unroll
        for (int j = 0; j < 4; ++j) {
            float v2  = __expf(l2[j]);
            float iv2 = __expf(-l2[j]);
            float s   = v1[j] + v2 + 1e-6f;
            float diff = m1[j] - m2[j];
            z += diff * diff * __builtin_amdgcn_rcpf(s) + __logf(s);
            float iv_new = iv1[j] + iv2;
            float cvar   = __builtin_amdgcn_rcpf(iv_new);
            m1[j]  = cvar * (m1[j] * iv1[j] + m2[j] * iv2);
            v1[j]  = cvar;
            iv1[j] = iv_new;
        }
    }

    // ---- elementwise outputs ----
    float4 om = make_float4(m1[0], m1[1], m1[2], m1[3]);
    float4 ol = make_float4(__logf(v1[0]), __logf(v1[1]),
                            __logf(v1[2]), __logf(v1[3]));
    *(float4*)(out_mean + rowoff)   = om;
    *(float4*)(out_logvar + rowoff) = ol;

    // ---- row reduction of z (256 threads = 4 waves of 64) ----
#pragma unroll
    for (int o = 32; o > 0; o >>= 1)
        z += __shfl_down(z, o, 64);

    __shared__ float sz[4];
    const int lane = t & 63;
    if (lane == 0) sz[wave] = z;
    __syncthreads();
    if (t == 0) {
        float total = sz[0] + sz[1] + sz[2] + sz[3];
        out_logz[b] = -0.5f * (total + (float)((NN - 1) * DD) * LOG_2PI);
    }
}

extern "C" void kernel_launch(void* const* d_in, const int* in_sizes, int n_in,
                              void* d_out, int out_size, void* d_ws, size_t ws_size,
                              hipStream_t stream) {
    const float* means  = (const float*)d_in[0];
    const float* logsig = (const float*)d_in[1];
    float* out = (float*)d_out;
    float* out_mean   = out;
    float* out_logvar = out + (size_t)BB * DD;
    float* out_logz   = out + 2 * (size_t)BB * DD;
    mpc_kernel<<<BB, 256, 0, stream>>>(means, logsig, out_mean, out_logvar, out_logz);
}